// Round 1
// baseline (1347.911 us; speedup 1.0000x reference)
//
#include <hip/hip_runtime.h>
#include <math.h>

#define EPSV 1e-5f
#define B 8
#define C 1024
#define C2 512
#define RK 73
#define H 28
#define W 28
#define HW 784      // 28*28
#define H2 56
#define QW 3136     // 56*56

// ---------- kernel 1: global average pool over y -> s0 (B*C2) ----------
__global__ void gap_kernel(const float* __restrict__ y, float* __restrict__ s0) {
    int bc = blockIdx.x;  // b*C2 + c
    const float* p = y + (size_t)bc * QW;
    float sum = 0.f;
    for (int i = threadIdx.x; i < QW; i += 256) sum += p[i];
    for (int off = 32; off > 0; off >>= 1) sum += __shfl_down(sum, off, 64);
    __shared__ float red[4];
    if ((threadIdx.x & 63) == 0) red[threadIdx.x >> 6] = sum;
    __syncthreads();
    if (threadIdx.x == 0)
        s0[bc] = (red[0] + red[1] + red[2] + red[3]) * (1.0f / QW);
}

// ---------- kernel 2: SE FC layers -> att = sigmoid(fc2(relu(fc1(s0)))) ----------
__global__ void se_fc_kernel(const float* __restrict__ s0,
                             const float* __restrict__ fc1_w,
                             const float* __restrict__ fc2_w,
                             float* __restrict__ att) {
    int b = blockIdx.x;
    __shared__ float sv[C2];
    __shared__ float hv[RK];
    for (int i = threadIdx.x; i < C2; i += 256) sv[i] = s0[b * C2 + i];
    __syncthreads();
    if (threadIdx.x < RK) {
        float acc = 0.f;
        const float* wr = fc1_w + threadIdx.x * C2;
        for (int k = 0; k < C2; ++k) acc += wr[k] * sv[k];
        hv[threadIdx.x] = fmaxf(acc, 0.f);
    }
    __syncthreads();
    for (int o = threadIdx.x; o < C2; o += 256) {
        float acc = 0.f;
        const float* wr = fc2_w + o * RK;
        for (int j = 0; j < RK; ++j) acc += wr[j] * hv[j];
        att[b * C2 + o] = 1.f / (1.f + expf(-acc));
    }
}

// ---------- kernel 3: depthwise 3x3 conv + per-row centering + cov ----------
__global__ void dwcov_kernel(const float* __restrict__ x,
                             const float* __restrict__ dw_w,
                             const float* __restrict__ dw_b,
                             float* __restrict__ cov) {
    int bc = blockIdx.x;            // b*C + c
    int c = bc & (C - 1);
    __shared__ float xs[HW];
    __shared__ float x1[HW];
    __shared__ float rm[H];
    const float* px = x + (size_t)bc * HW;
    for (int i = threadIdx.x; i < HW; i += 256) xs[i] = px[i];
    float wk[9];
#pragma unroll
    for (int j = 0; j < 9; ++j) wk[j] = dw_w[c * 9 + j];
    float bias = dw_b[c];
    __syncthreads();
    for (int p = threadIdx.x; p < HW; p += 256) {
        int h = p / 28, w = p - h * 28;
        float acc = bias;
#pragma unroll
        for (int dh = 0; dh < 3; ++dh) {
            int hh = h + dh - 1;
            if (hh < 0 || hh >= H) continue;
#pragma unroll
            for (int dw = 0; dw < 3; ++dw) {
                int ww = w + dw - 1;
                if (ww < 0 || ww >= W) continue;
                acc += xs[hh * 28 + ww] * wk[dh * 3 + dw];
            }
        }
        x1[p] = acc;
    }
    __syncthreads();
    if (threadIdx.x < H) {
        float s = 0.f;
        for (int w = 0; w < W; ++w) s += x1[threadIdx.x * 28 + w];
        rm[threadIdx.x] = s * (1.f / 28.f);
    }
    __syncthreads();
    float* pc = cov + (size_t)bc * HW;
    for (int p = threadIdx.x; p < HW; p += 256) {
        int h = p / 28, g = p - h * 28;
        float mh = rm[h], mg = rm[g];
        float acc = 0.f;
        for (int w = 0; w < W; ++w)
            acc += (x1[h * 28 + w] - mh) * (x1[g * 28 + w] - mg);
        pc[p] = acc * (1.f / 27.f);
    }
}

// ---------- kernel 4: 1x1 conv C->C2 over cov + bn + sigmoid -> x2s ----------
// GEMM per batch: (C2 x C) @ (C x 784). Tile 64o x 64p, K-chunk 16.
__global__ void conv_bn_sig_kernel(const float* __restrict__ cov,
                                   const float* __restrict__ conv_w,
                                   const float* __restrict__ conv_b,
                                   const float* __restrict__ bn_g,
                                   const float* __restrict__ bn_b,
                                   const float* __restrict__ bn_m,
                                   const float* __restrict__ bn_v,
                                   float* __restrict__ x2s) {
    int b = blockIdx.z;
    int o0 = blockIdx.y * 64;
    int p0 = blockIdx.x * 64;
    __shared__ __align__(16) float Wt[16][68];  // [k][o_local], 16B-aligned rows
    __shared__ __align__(16) float At[16][68];  // [k][p_local]
    int tid = threadIdx.x;
    int tx = tid & 15, ty = tid >> 4;
    float acc[4][4] = {};
    for (int k0 = 0; k0 < C; k0 += 16) {
#pragma unroll
        for (int l = 0; l < 4; ++l) {
            int e = tid + l * 256;
            int r = e >> 4, cc = e & 15;          // r: o_local, cc: k_local
            Wt[cc][r] = conv_w[(o0 + r) * C + k0 + cc];
        }
#pragma unroll
        for (int l = 0; l < 4; ++l) {
            int e = tid + l * 256;
            int r = e >> 6, cc = e & 63;          // r: k_local, cc: p_local
            int p = p0 + cc;
            At[r][cc] = (p < HW) ? cov[(size_t)(b * C + k0 + r) * HW + p] : 0.f;
        }
        __syncthreads();
#pragma unroll
        for (int kk = 0; kk < 16; ++kk) {
            float aw[4], av[4];
            *(float4*)aw = *(const float4*)&Wt[kk][ty * 4];
            *(float4*)av = *(const float4*)&At[kk][tx * 4];
#pragma unroll
            for (int i = 0; i < 4; ++i)
#pragma unroll
                for (int j = 0; j < 4; ++j)
                    acc[i][j] = fmaf(aw[i], av[j], acc[i][j]);
        }
        __syncthreads();
    }
#pragma unroll
    for (int i = 0; i < 4; ++i) {
        int o = o0 + ty * 4 + i;
        float sc = rsqrtf(bn_v[o] + EPSV) * bn_g[o];
        float bi = bn_b[o] - bn_m[o] * sc;
        float cb = conv_b[o];
#pragma unroll
        for (int j = 0; j < 4; ++j) {
            int p = p0 + tx * 4 + j;
            if (p < HW) {
                float v = (acc[i][j] + cb) * sc + bi;
                x2s[(size_t)(b * C2 + o) * HW + p] = 1.f / (1.f + expf(-v));
            }
        }
    }
}

// 2x bilinear (half-pixel, edge-clamped) sample of a 28x28 map at output (hq,wq)
__device__ __forceinline__ float bilerp28(const float* __restrict__ t, int hq, int wq) {
    int hm = hq >> 1;
    int hn = (hq & 1) ? min(hm + 1, 27) : max(hm - 1, 0);
    int wm = wq >> 1;
    int wn = (wq & 1) ? min(wm + 1, 27) : max(wm - 1, 0);
    float a = t[hm * 28 + wm];
    float bb = t[hm * 28 + wn];
    float cc = t[hn * 28 + wm];
    float d = t[hn * 28 + wn];
    return 0.5625f * a + 0.1875f * (bb + cc) + 0.0625f * d;
}

// ---------- kernel 5: fused gather(cat) + 1x1 conv 2048->512 + bn + relu ----------
// GEMM per batch: (C2 x 2048) @ (2048 x 3136). Tile 64o x 64q, K-chunk 16.
__global__ void final_kernel(const float* __restrict__ y,
                             const float* __restrict__ att,
                             const float* __restrict__ x2s,
                             const float* __restrict__ x,
                             const float* __restrict__ conv1_w,
                             const float* __restrict__ conv1_b,
                             const float* __restrict__ bn_g,
                             const float* __restrict__ bn_b,
                             const float* __restrict__ bn_m,
                             const float* __restrict__ bn_v,
                             float* __restrict__ out) {
    int b = blockIdx.z;
    int o0 = blockIdx.y * 64;
    int q0 = blockIdx.x * 64;   // 3136 = 49*64, exact
    __shared__ __align__(16) float Wt[16][68];
    __shared__ __align__(16) float At[16][68];
    int tid = threadIdx.x;
    int tx = tid & 15, ty = tid >> 4;
    float acc[4][4] = {};
    for (int k0 = 0; k0 < 2 * C; k0 += 16) {
#pragma unroll
        for (int l = 0; l < 4; ++l) {
            int e = tid + l * 256;
            int r = e >> 4, cc = e & 15;
            Wt[cc][r] = conv1_w[(o0 + r) * (2 * C) + k0 + cc];
        }
#pragma unroll
        for (int l = 0; l < 4; ++l) {
            int e = tid + l * 256;
            int r = e >> 6, cc = e & 63;     // r: k_local (wave-uniform), cc: q_local
            int ch = k0 + r;                 // channel in cat, wave-uniform
            int q = q0 + cc;
            float v;
            if (ch < C2) {
                v = y[(size_t)(b * C2 + ch) * QW + q] * att[b * C2 + ch];
            } else if (ch < 2 * C2) {
                const float* t = x2s + (size_t)(b * C2 + (ch - C2)) * HW;
                int hq = q / 56, wq = q - hq * 56;
                v = bilerp28(t, hq, wq);
            } else {
                const float* t = x + (size_t)(b * C + (ch - 2 * C2)) * HW;
                int hq = q / 56, wq = q - hq * 56;
                v = bilerp28(t, hq, wq);
            }
            At[r][cc] = v;
        }
        __syncthreads();
#pragma unroll
        for (int kk = 0; kk < 16; ++kk) {
            float aw[4], av[4];
            *(float4*)aw = *(const float4*)&Wt[kk][ty * 4];
            *(float4*)av = *(const float4*)&At[kk][tx * 4];
#pragma unroll
            for (int i = 0; i < 4; ++i)
#pragma unroll
                for (int j = 0; j < 4; ++j)
                    acc[i][j] = fmaf(aw[i], av[j], acc[i][j]);
        }
        __syncthreads();
    }
#pragma unroll
    for (int i = 0; i < 4; ++i) {
        int o = o0 + ty * 4 + i;
        float sc = rsqrtf(bn_v[o] + EPSV) * bn_g[o];
        float bi = bn_b[o] - bn_m[o] * sc;
        float cb = conv1_b[o];
#pragma unroll
        for (int j = 0; j < 4; ++j) {
            int q = q0 + tx * 4 + j;
            float v = (acc[i][j] + cb) * sc + bi;
            out[(size_t)(b * C2 + o) * QW + q] = fmaxf(v, 0.f);
        }
    }
}

extern "C" void kernel_launch(void* const* d_in, const int* in_sizes, int n_in,
                              void* d_out, int out_size, void* d_ws, size_t ws_size,
                              hipStream_t stream) {
    const float* y       = (const float*)d_in[0];
    const float* x       = (const float*)d_in[1];
    const float* fc1_w   = (const float*)d_in[2];
    const float* fc2_w   = (const float*)d_in[3];
    const float* conv_w  = (const float*)d_in[4];
    const float* conv_b  = (const float*)d_in[5];
    const float* conv1_w = (const float*)d_in[6];
    const float* conv1_b = (const float*)d_in[7];
    const float* bn_g    = (const float*)d_in[8];
    const float* bn_b    = (const float*)d_in[9];
    const float* bn_m    = (const float*)d_in[10];
    const float* bn_v    = (const float*)d_in[11];
    const float* dw_w    = (const float*)d_in[12];
    const float* dw_b    = (const float*)d_in[13];
    float* out = (float*)d_out;

    float* ws  = (float*)d_ws;
    float* s0  = ws;                       // 4096 floats
    float* att = ws + 4096;                // 4096 floats
    float* cov = ws + 8192;                // 8*1024*784 = 6,422,528 floats
    float* x2s = cov + (size_t)B * C * HW; // 8*512*784  = 3,211,264 floats
    // total ws use: ~38.6 MB

    gap_kernel<<<B * C2, 256, 0, stream>>>(y, s0);
    se_fc_kernel<<<B, 256, 0, stream>>>(s0, fc1_w, fc2_w, att);
    dwcov_kernel<<<B * C, 256, 0, stream>>>(x, dw_w, dw_b, cov);
    dim3 g4(13, 8, 8);   // ceil(784/64), 512/64, B
    conv_bn_sig_kernel<<<g4, 256, 0, stream>>>(cov, conv_w, conv_b,
                                               bn_g, bn_b, bn_m, bn_v, x2s);
    dim3 g5(49, 8, 8);   // 3136/64, 512/64, B
    final_kernel<<<g5, 256, 0, stream>>>(y, att, x2s, x, conv1_w, conv1_b,
                                         bn_g, bn_b, bn_m, bn_v, out);
}

// Round 2
// 496.542 us; speedup vs baseline: 2.7146x; 2.7146x over previous
//
#include <hip/hip_runtime.h>
#include <math.h>

#define EPSV 1e-5f
#define B 8
#define C 1024
#define C2 512
#define RK 73
#define H 28
#define HW 784      // 28*28
#define QW 3136     // 56*56

typedef __attribute__((ext_vector_type(8))) short bf16x8;
typedef __attribute__((ext_vector_type(4))) float f32x4;

__device__ __forceinline__ unsigned short f2bf(float f) {
    unsigned u = __float_as_uint(f);
    unsigned r = (u + 0x7fffu + ((u >> 16) & 1u)) >> 16;
    return (unsigned short)r;
}

// ---------- kernel 1: global average pool over y -> s0 (B*C2) ----------
__global__ void gap_kernel(const float* __restrict__ y, float* __restrict__ s0) {
    int bc = blockIdx.x;
    const float* p = y + (size_t)bc * QW;
    float sum = 0.f;
    for (int i = threadIdx.x; i < QW; i += 256) sum += p[i];
    for (int off = 32; off > 0; off >>= 1) sum += __shfl_down(sum, off, 64);
    __shared__ float red[4];
    if ((threadIdx.x & 63) == 0) red[threadIdx.x >> 6] = sum;
    __syncthreads();
    if (threadIdx.x == 0)
        s0[bc] = (red[0] + red[1] + red[2] + red[3]) * (1.0f / QW);
}

// ---------- kernel 2: SE FC layers ----------
__global__ void se_fc_kernel(const float* __restrict__ s0,
                             const float* __restrict__ fc1_w,
                             const float* __restrict__ fc2_w,
                             float* __restrict__ att) {
    int b = blockIdx.x;
    __shared__ float sv[C2];
    __shared__ float hv[RK];
    for (int i = threadIdx.x; i < C2; i += 256) sv[i] = s0[b * C2 + i];
    __syncthreads();
    if (threadIdx.x < RK) {
        float acc = 0.f;
        const float* wr = fc1_w + threadIdx.x * C2;
        for (int k = 0; k < C2; ++k) acc += wr[k] * sv[k];
        hv[threadIdx.x] = fmaxf(acc, 0.f);
    }
    __syncthreads();
    for (int o = threadIdx.x; o < C2; o += 256) {
        float acc = 0.f;
        const float* wr = fc2_w + o * RK;
        for (int j = 0; j < RK; ++j) acc += wr[j] * hv[j];
        att[b * C2 + o] = 1.f / (1.f + expf(-acc));
    }
}

// ---------- kernel 3: depthwise 3x3 conv + row-centered cov ----------
__global__ void dwcov_kernel(const float* __restrict__ x,
                             const float* __restrict__ dw_w,
                             const float* __restrict__ dw_b,
                             float* __restrict__ cov) {
    int bc = blockIdx.x;
    int c = bc & (C - 1);
    __shared__ float xs[HW];
    __shared__ float x1[HW];
    __shared__ float rm[H];
    const float* px = x + (size_t)bc * HW;
    for (int i = threadIdx.x; i < HW; i += 256) xs[i] = px[i];
    float wk[9];
#pragma unroll
    for (int j = 0; j < 9; ++j) wk[j] = dw_w[c * 9 + j];
    float bias = dw_b[c];
    __syncthreads();
    for (int p = threadIdx.x; p < HW; p += 256) {
        int h = p / 28, w = p - h * 28;
        float acc = bias;
#pragma unroll
        for (int dh = 0; dh < 3; ++dh) {
            int hh = h + dh - 1;
            if (hh < 0 || hh >= H) continue;
#pragma unroll
            for (int dw = 0; dw < 3; ++dw) {
                int ww = w + dw - 1;
                if (ww < 0 || ww >= 28) continue;
                acc += xs[hh * 28 + ww] * wk[dh * 3 + dw];
            }
        }
        x1[p] = acc;
    }
    __syncthreads();
    if (threadIdx.x < H) {
        float s = 0.f;
        for (int w = 0; w < 28; ++w) s += x1[threadIdx.x * 28 + w];
        rm[threadIdx.x] = s * (1.f / 28.f);
    }
    __syncthreads();
    float* pc = cov + (size_t)bc * HW;
    for (int p = threadIdx.x; p < HW; p += 256) {
        int h = p / 28, g = p - h * 28;
        float mh = rm[h], mg = rm[g];
        float acc = 0.f;
        for (int w = 0; w < 28; ++w)
            acc += (x1[h * 28 + w] - mh) * (x1[g * 28 + w] - mg);
        pc[p] = acc * (1.f / 27.f);
    }
}

// ---------- prep: pack weights to bf16 [o][k]; fold bias+bn into scale/bias ----------
__global__ void pack_kernel(const float* __restrict__ conv_w, const float* __restrict__ conv_b,
                            const float* __restrict__ conv1_w, const float* __restrict__ conv1_b,
                            const float* __restrict__ bn_g, const float* __restrict__ bn_b,
                            const float* __restrict__ bn_m, const float* __restrict__ bn_v,
                            unsigned short* __restrict__ w0b, unsigned short* __restrict__ w1b,
                            float* __restrict__ sA, float* __restrict__ sB0, float* __restrict__ sB1) {
    int o = blockIdx.x;
    for (int i = threadIdx.x; i < 2048; i += 256) w1b[(size_t)o * 2048 + i] = f2bf(conv1_w[(size_t)o * 2048 + i]);
    for (int i = threadIdx.x; i < 1024; i += 256) w0b[(size_t)o * 1024 + i] = f2bf(conv_w[(size_t)o * 1024 + i]);
    if (threadIdx.x == 0) {
        float sc = rsqrtf(bn_v[o] + EPSV) * bn_g[o];
        float bi = bn_b[o] - bn_m[o] * sc;
        sA[o] = sc;
        sB0[o] = conv_b[o] * sc + bi;
        sB1[o] = conv1_b[o] * sc + bi;
    }
}

// ---------- MFMA GEMM: C[o][q] = sum_ch W[o][ch] * Bmat[ch][q], per batch ----------
// MODE 0: Bmat = cov (f32 direct), N=784, K=1024, epilogue sigmoid -> x2s
// MODE 1: Bmat = gathered cat (y*att | up(x2s) | up(x)), N=3136, K=2048, epilogue relu -> out
template<int MODE, int K, int NQ>
__global__ __launch_bounds__(256)
void mfma_gemm(const unsigned short* __restrict__ wpk,
               const float* __restrict__ covp,
               const float* __restrict__ y, const float* __restrict__ att,
               const float* __restrict__ x2s, const float* __restrict__ x,
               const float* __restrict__ sA, const float* __restrict__ sB,
               float* __restrict__ outp) {
    int b = blockIdx.z;
    int o0 = blockIdx.y * 128;
    int q0 = blockIdx.x * 64;
    __shared__ __align__(16) unsigned short Wt[128 * 40];
    __shared__ __align__(16) unsigned short At[64 * 40];
    __shared__ float att_s[C2];
    int tid = threadIdx.x;
    int lane = tid & 63, wv = tid >> 6;
    int ln = lane & 15, quad = lane >> 4;
    int o_w = (wv >> 1) * 64, q_w = (wv & 1) * 32;
    // staging thread mapping
    int sr = tid >> 1, skh = (tid & 1) * 16;   // W: row, k-half
    int gq = tid & 63, gk8 = tid >> 6;         // B: q within tile, k-octet
    int qg = q0 + gq;
    int i00 = 0, i01 = 0, i10 = 0, i11 = 0;
    if (MODE == 1) {
        for (int i = tid; i < C2; i += 256) att_s[i] = att[b * C2 + i];
        int hq = qg / 56, wq = qg - hq * 56;
        int hm = hq >> 1, wm = wq >> 1;
        int hn = (hq & 1) ? min(hm + 1, 27) : max(hm - 1, 0);
        int wn = (wq & 1) ? min(wm + 1, 27) : max(wm - 1, 0);
        i00 = hm * 28 + wm; i01 = hm * 28 + wn; i10 = hn * 28 + wm; i11 = hn * 28 + wn;
    }
    f32x4 acc[4][2] = {};
    for (int k0 = 0; k0 < K; k0 += 32) {
        __syncthreads();
        // ---- stage W tile: [128 o][32 k] bf16, row pitch 40 ----
        {
            const unsigned short* src = wpk + (size_t)(o0 + sr) * K + k0 + skh;
            float4 va = *(const float4*)src;
            float4 vb = *(const float4*)(src + 8);
            *(float4*)&Wt[sr * 40 + skh] = va;
            *(float4*)&Wt[sr * 40 + skh + 8] = vb;
        }
        // ---- stage B tile: [64 q][32 k] bf16, row pitch 40 ----
        {
            unsigned short pk[8];
            int ch = k0 + gk8 * 8;
            if (MODE == 0) {
                bool inb = qg < NQ;
                const float* src = covp + ((size_t)b * K + ch) * 784 + qg;
#pragma unroll
                for (int j = 0; j < 8; ++j) pk[j] = inb ? f2bf(src[(size_t)j * 784]) : (unsigned short)0;
            } else {
                if (ch < C2) {
                    const float* src = y + ((size_t)b * C2 + ch) * QW + qg;
#pragma unroll
                    for (int j = 0; j < 8; ++j) pk[j] = f2bf(src[(size_t)j * QW] * att_s[ch + j]);
                } else if (ch < 2 * C2) {
                    const float* m = x2s + ((size_t)b * C2 + (ch - C2)) * HW;
#pragma unroll
                    for (int j = 0; j < 8; ++j) {
                        const float* mm = m + (size_t)j * HW;
                        pk[j] = f2bf(0.5625f * mm[i00] + 0.1875f * (mm[i01] + mm[i10]) + 0.0625f * mm[i11]);
                    }
                } else {
                    const float* m = x + ((size_t)b * C + (ch - 2 * C2)) * HW;
#pragma unroll
                    for (int j = 0; j < 8; ++j) {
                        const float* mm = m + (size_t)j * HW;
                        pk[j] = f2bf(0.5625f * mm[i00] + 0.1875f * (mm[i01] + mm[i10]) + 0.0625f * mm[i11]);
                    }
                }
            }
            *(float4*)&At[gq * 40 + gk8 * 8] = *(float4*)pk;
        }
        __syncthreads();
        // ---- MFMA: wave tile 64o x 32q ----
        bf16x8 af[4], bfr[2];
#pragma unroll
        for (int mt = 0; mt < 4; ++mt)
            af[mt] = *(const bf16x8*)&Wt[(o_w + mt * 16 + ln) * 40 + quad * 8];
#pragma unroll
        for (int nt = 0; nt < 2; ++nt)
            bfr[nt] = *(const bf16x8*)&At[(q_w + nt * 16 + ln) * 40 + quad * 8];
#pragma unroll
        for (int mt = 0; mt < 4; ++mt)
#pragma unroll
            for (int nt = 0; nt < 2; ++nt)
                acc[mt][nt] = __builtin_amdgcn_mfma_f32_16x16x32_bf16(af[mt], bfr[nt], acc[mt][nt], 0, 0, 0);
    }
    // ---- epilogue: D row = quad*4+reg, col = ln ----
#pragma unroll
    for (int mt = 0; mt < 4; ++mt) {
#pragma unroll
        for (int reg = 0; reg < 4; ++reg) {
            int o = o0 + o_w + mt * 16 + quad * 4 + reg;
            float sc = sA[o], sb = sB[o];
#pragma unroll
            for (int nt = 0; nt < 2; ++nt) {
                int q = q0 + q_w + nt * 16 + ln;
                float v = acc[mt][nt][reg] * sc + sb;
                if (MODE == 1) {
                    outp[((size_t)b * C2 + o) * QW + q] = fmaxf(v, 0.f);
                } else if (q < NQ) {
                    outp[((size_t)b * C2 + o) * HW + q] = 1.f / (1.f + expf(-v));
                }
            }
        }
    }
}

extern "C" void kernel_launch(void* const* d_in, const int* in_sizes, int n_in,
                              void* d_out, int out_size, void* d_ws, size_t ws_size,
                              hipStream_t stream) {
    const float* y       = (const float*)d_in[0];
    const float* x       = (const float*)d_in[1];
    const float* fc1_w   = (const float*)d_in[2];
    const float* fc2_w   = (const float*)d_in[3];
    const float* conv_w  = (const float*)d_in[4];
    const float* conv_b  = (const float*)d_in[5];
    const float* conv1_w = (const float*)d_in[6];
    const float* conv1_b = (const float*)d_in[7];
    const float* bn_g    = (const float*)d_in[8];
    const float* bn_b    = (const float*)d_in[9];
    const float* bn_m    = (const float*)d_in[10];
    const float* bn_v    = (const float*)d_in[11];
    const float* dw_w    = (const float*)d_in[12];
    const float* dw_b    = (const float*)d_in[13];
    float* out = (float*)d_out;

    float* ws  = (float*)d_ws;
    float* s0  = ws;                            // 4096
    float* att = s0 + 4096;                     // 4096
    float* sA  = att + 4096;                    // 512
    float* sB0 = sA + 512;                      // 512
    float* sB1 = sB0 + 512;                     // 512
    float* cov = sB1 + 512;                     // 8*1024*784
    float* x2s = cov + (size_t)B * C * HW;      // 8*512*784
    unsigned short* w0b = (unsigned short*)(x2s + (size_t)B * C2 * HW);  // 512*1024
    unsigned short* w1b = w0b + (size_t)C2 * C;                          // 512*2048
    // total ws use ~41.7 MB

    pack_kernel<<<C2, 256, 0, stream>>>(conv_w, conv_b, conv1_w, conv1_b,
                                        bn_g, bn_b, bn_m, bn_v, w0b, w1b, sA, sB0, sB1);
    gap_kernel<<<B * C2, 256, 0, stream>>>(y, s0);
    se_fc_kernel<<<B, 256, 0, stream>>>(s0, fc1_w, fc2_w, att);
    dwcov_kernel<<<B * C, 256, 0, stream>>>(x, dw_w, dw_b, cov);
    dim3 g0(13, 4, 8);   // ceil(784/64), 512/128, B
    mfma_gemm<0, 1024, 784><<<g0, 256, 0, stream>>>(w0b, cov, nullptr, nullptr, nullptr, nullptr,
                                                    sA, sB0, x2s);
    dim3 g1(49, 4, 8);   // 3136/64, 512/128, B
    mfma_gemm<1, 2048, 3136><<<g1, 256, 0, stream>>>(w1b, nullptr, y, att, x2s, x,
                                                     sA, sB1, out);
}